// Round 8
// baseline (77.177 us; speedup 1.0000x reference)
//
#include <hip/hip_runtime.h>

#define DMODEL 1024
#define DHEAD 128
#define CHUNK 128
#define NCHUNK 32

typedef __attribute__((ext_vector_type(4))) float f32x4;
typedef __attribute__((ext_vector_type(8))) short bf16x8;

__device__ __forceinline__ unsigned short f2bf(float f) {
  union { float f; unsigned u; } v; v.f = f;
  unsigned r = v.u + 0x7FFF + ((v.u >> 16) & 1);   // RNE
  return (unsigned short)(r >> 16);
}
__device__ __forceinline__ float bf2f(unsigned short h) {
  union { unsigned u; float f; } v; v.u = ((unsigned)h) << 16;
  return v.f;
}
__device__ __forceinline__ unsigned cvtpk(float lo, float hi) {
  unsigned r;
  asm("v_cvt_pk_bf16_f32 %0, %1, %2" : "=v"(r) : "v"(lo), "v"(hi));
  return r;
}
__device__ __forceinline__ void gload16(const void* g, void* l) {
  __builtin_amdgcn_global_load_lds(
      (const __attribute__((address_space(1))) unsigned int*)g,
      (__attribute__((address_space(3))) unsigned int*)l, 16, 0, 0);
}

// ---------------- K0: W -> W^T bf16 [which][n][k] ----------------
__global__ __launch_bounds__(256) void transpose_w_kernel(
    const float* __restrict__ Wq, const float* __restrict__ Wk,
    const float* __restrict__ Wv, unsigned short* __restrict__ WT) {
  int id = blockIdx.x * 256 + threadIdx.x;
  int w = id >> 17;
  int rem = id & 131071;
  int n = rem >> 10;
  int k = rem & 1023;
  const float* W = (w == 0) ? Wq : (w == 1) ? Wk : Wv;
  WT[id] = f2bf(W[(size_t)k * DHEAD + n]);
}

// ---------------- K1: fused projection GEMM + phi (2-phase dbuf) ----------------
// grid (256, 3): BM=64, BN=128, BK=64, 128 threads (2 waves).
__device__ __forceinline__ void stage_tiles(
    const float* __restrict__ x, const unsigned short* __restrict__ Wt,
    int m0, int kk, float (*xsb)[64], unsigned short (*wsb)[64],
    int wave, int lane) {
#pragma unroll
  for (int i = 0; i < 8; ++i) {
    int instr = i * 2 + wave;
    int row = instr * 4 + (lane >> 4);
    int slot = lane & 15;
    int gcol = (slot ^ (row & 7)) << 2;
    gload16(&x[(size_t)(m0 + row) * DMODEL + kk + gcol],
            (char*)xsb + instr * 1024);
  }
#pragma unroll
  for (int i = 0; i < 8; ++i) {
    int instr = i * 2 + wave;
    int row = instr * 8 + (lane >> 3);
    int slot = lane & 7;
    int gcol = (slot ^ (row & 7)) << 3;
    gload16(&Wt[(size_t)row * DMODEL + kk + gcol],
            (char*)wsb + instr * 1024);
  }
}

__global__ __launch_bounds__(128) void proj_kernel(
    const float* __restrict__ x, const unsigned short* __restrict__ WT,
    unsigned short* __restrict__ phiQ, unsigned short* __restrict__ phiK,
    unsigned short* __restrict__ Vb) {
  const int which = blockIdx.y;
  const unsigned short* Wt = WT + (size_t)which * (DHEAD * DMODEL);
  unsigned short* outp = (which == 0) ? phiQ : (which == 1) ? phiK : Vb;
  const int m0 = blockIdx.x * 64;

  __shared__ float xs[2][64][64];            // 32 KB total
  __shared__ unsigned short wsl[2][128][64]; // 32 KB total

  const int tid = threadIdx.x;
  const int wave = tid >> 6;
  const int lane = tid & 63;
  const int lrow = lane & 15, kgrp = lane >> 4;

  f32x4 acc[2][8];
#pragma unroll
  for (int i = 0; i < 2; ++i)
#pragma unroll
    for (int j = 0; j < 8; ++j) acc[i][j] = (f32x4)0.0f;

  stage_tiles(x, Wt, m0, 0, xs[0], wsl[0], wave, lane);
  int cur = 0;
  for (int kk = 0; kk < DMODEL; kk += 64) {
    if (kk + 64 < DMODEL) {
      stage_tiles(x, Wt, m0, kk + 64, xs[cur ^ 1], wsl[cur ^ 1], wave, lane);
      asm volatile("s_waitcnt vmcnt(16)" ::: "memory");   // cur tile done; 16 prefetch in flight
    } else {
      asm volatile("s_waitcnt vmcnt(0)" ::: "memory");
    }
    __builtin_amdgcn_s_barrier();
    __builtin_amdgcn_sched_barrier(0);

#pragma unroll
    for (int ks2 = 0; ks2 < 2; ++ks2) {
      bf16x8 af[2];
#pragma unroll
      for (int mr = 0; mr < 2; ++mr) {
        int arow = wave * 32 + mr * 16 + lrow;
        int s0 = ks2 * 8 + kgrp * 2;
        const float4 f0 = *reinterpret_cast<const float4*>(
            &xs[cur][arow][(s0 ^ (arow & 7)) << 2]);
        const float4 f1 = *reinterpret_cast<const float4*>(
            &xs[cur][arow][((s0 + 1) ^ (arow & 7)) << 2]);
        union { unsigned u[4]; bf16x8 v; } p;
        p.u[0] = cvtpk(f0.x, f0.y);
        p.u[1] = cvtpk(f0.z, f0.w);
        p.u[2] = cvtpk(f1.x, f1.y);
        p.u[3] = cvtpk(f1.z, f1.w);
        af[mr] = p.v;
      }
#pragma unroll
      for (int nr = 0; nr < 8; ++nr) {
        int brow = nr * 16 + lrow;
        int bs = ks2 * 4 + kgrp;
        bf16x8 bf = *reinterpret_cast<const bf16x8*>(
            &wsl[cur][brow][(bs ^ (brow & 7)) << 3]);
        acc[0][nr] = __builtin_amdgcn_mfma_f32_16x16x32_bf16(af[0], bf, acc[0][nr], 0, 0, 0);
        acc[1][nr] = __builtin_amdgcn_mfma_f32_16x16x32_bf16(af[1], bf, acc[1][nr], 0, 0, 0);
      }
    }
    __builtin_amdgcn_sched_barrier(0);
    __builtin_amdgcn_s_barrier();          // all waves done reading before overwrite
    cur ^= 1;
  }
  // epilogue: phi for q/k, plain for v; store bf16
#pragma unroll
  for (int mr = 0; mr < 2; ++mr)
#pragma unroll
    for (int nr = 0; nr < 8; ++nr)
#pragma unroll
      for (int r = 0; r < 4; ++r) {
        int row = m0 + wave * 32 + mr * 16 + kgrp * 4 + r;
        int col = nr * 16 + lrow;
        float v = acc[mr][nr][r];
        if (which < 2) v = (v > 0.0f) ? (v + 1.0f) : __expf(v);
        outp[(size_t)row * DHEAD + col] = f2bf(v);
      }
}

// ---------------- K2: per-chunk KV^T = v^T @ k, ks colsums ----------------
__global__ __launch_bounds__(256) void chunkkv_kernel(
    const unsigned short* __restrict__ phiK, const unsigned short* __restrict__ Vb,
    float* __restrict__ KVc, float* __restrict__ ksc) {
  const size_t base = (size_t)blockIdx.x * CHUNK * DHEAD;
  __shared__ unsigned short kt[128][136];   // k^T [d][t]
  __shared__ unsigned short vt[128][136];   // v^T [dv][t]
  __shared__ float csum[2][128];
  const int tid = threadIdx.x;
  const int wave = tid >> 6, lane = tid & 63;
  const int lrow = lane & 15, kgrp = lane >> 4;

  // transposed staging: lanes vary t (conflict-free LDS writes)
  {
    int t = tid & 127, dp = tid >> 7;
#pragma unroll
    for (int i = 0; i < 8; ++i) {
      int d0 = (dp + 2 * i) * 8;
      uint4 k4 = *reinterpret_cast<const uint4*>(&phiK[base + (size_t)t * DHEAD + d0]);
      uint4 v4 = *reinterpret_cast<const uint4*>(&Vb[base + (size_t)t * DHEAD + d0]);
      const unsigned short* kp = reinterpret_cast<const unsigned short*>(&k4);
      const unsigned short* vp = reinterpret_cast<const unsigned short*>(&v4);
#pragma unroll
      for (int j = 0; j < 8; ++j) { kt[d0 + j][t] = kp[j]; vt[d0 + j][t] = vp[j]; }
    }
  }
  __syncthreads();

  f32x4 acc[2][8];
#pragma unroll
  for (int i = 0; i < 2; ++i)
#pragma unroll
    for (int j = 0; j < 8; ++j) acc[i][j] = (f32x4)0.0f;
#pragma unroll
  for (int ks = 0; ks < 4; ++ks) {
    int t0 = ks * 32 + kgrp * 8;
    bf16x8 afrag[2];
#pragma unroll
    for (int tr = 0; tr < 2; ++tr)
      afrag[tr] = *reinterpret_cast<const bf16x8*>(&vt[wave * 32 + tr * 16 + lrow][t0]);
#pragma unroll
    for (int tc = 0; tc < 8; ++tc) {
      bf16x8 bfrag = *reinterpret_cast<const bf16x8*>(&kt[tc * 16 + lrow][t0]);
      acc[0][tc] = __builtin_amdgcn_mfma_f32_16x16x32_bf16(afrag[0], bfrag, acc[0][tc], 0, 0, 0);
      acc[1][tc] = __builtin_amdgcn_mfma_f32_16x16x32_bf16(afrag[1], bfrag, acc[1][tc], 0, 0, 0);
    }
  }
  float* KVout = KVc + (size_t)blockIdx.x * (DHEAD * DHEAD);   // [dv][d]
#pragma unroll
  for (int tr = 0; tr < 2; ++tr)
#pragma unroll
    for (int tc = 0; tc < 8; ++tc)
#pragma unroll
      for (int r = 0; r < 4; ++r) {
        int dv = wave * 32 + tr * 16 + kgrp * 4 + r;
        int d = tc * 16 + lrow;
        KVout[dv * DHEAD + d] = acc[tr][tc][r];
      }
  {
    int d = tid & 127, hh = tid >> 7;
    float s = 0.0f;
    for (int t = hh * 64; t < hh * 64 + 64; ++t) s += bf2f(kt[d][t]);
    csum[hh][d] = s;
  }
  __syncthreads();
  if (tid < 128) ksc[(size_t)blockIdx.x * DHEAD + tid] = csum[0][tid] + csum[1][tid];
}

// ---------------- K3: exclusive prefix over chunks ----------------
__global__ __launch_bounds__(256) void prefix_kernel(
    const float* __restrict__ KVc, const float* __restrict__ ksc,
    unsigned short* __restrict__ KVp, float* __restrict__ ksp) {
  if (blockIdx.x < 256) {
    int id = blockIdx.x * 256 + threadIdx.x;
    int b = id >> 14;
    int e = id & 16383;
    size_t base = (size_t)b * NCHUNK * 16384 + e;
    float acc = 0.0f;
    for (int c = 0; c < NCHUNK; ++c) {
      KVp[base + (size_t)c * 16384] = f2bf(acc);
      acc += KVc[base + (size_t)c * 16384];
    }
  } else {
    for (int i = threadIdx.x; i < 512; i += 256) {
      int b = i >> 7, d = i & 127;
      size_t base = (size_t)b * NCHUNK * DHEAD + d;
      float acc = 0.0f;
      for (int c = 0; c < NCHUNK; ++c) {
        ksp[base + (size_t)c * DHEAD] = acc;
        acc += ksc[base + (size_t)c * DHEAD];
      }
    }
  }
}

// ---------------- K4: per-chunk output, split in q-row halves ----------------
// grid (128, 2): blockIdx.x = chunk, blockIdx.y = h (q rows h*64..h*64+63).
__global__ __launch_bounds__(256) void out_kernel(
    const unsigned short* __restrict__ phiQ, const unsigned short* __restrict__ phiK,
    const unsigned short* __restrict__ Vb, const unsigned short* __restrict__ KVp,
    const float* __restrict__ ksp, float* __restrict__ outp) {
  const int c = blockIdx.x;
  const int h = blockIdx.y;
  const size_t kvbase = (size_t)c * CHUNK * DHEAD;
  const size_t qbase = kvbase + (size_t)h * 64 * DHEAD;
  __shared__ unsigned short qb[64][136];    // q rows (this half)
  __shared__ unsigned short kb[128][136];   // k rows 0..(h+1)*64; P overwrites rows 0..63
  __shared__ unsigned short vt[128][136];   // v^T [dv][t]; later KV [dv][d]
  __shared__ float dsum[4][64];
  __shared__ float ks_l[128];
  const int tid = threadIdx.x;
  const int wave = tid >> 6, lane = tid & 63;
  const int lrow = lane & 15, kgrp = lane >> 4;

  // stage q (coalesced)
#pragma unroll
  for (int it = 0; it < 4; ++it) {
    int idx = it * 256 + tid;
    int t = idx >> 4;
    int d0 = (idx & 15) << 3;
    *reinterpret_cast<uint4*>(&qb[t][d0]) =
        *reinterpret_cast<const uint4*>(&phiQ[qbase + (size_t)t * DHEAD + d0]);
  }
  if (tid < 128) ks_l[tid] = ksp[(size_t)c * DHEAD + tid];
  if (h == 0) {
    // k rows 0..63
#pragma unroll
    for (int it = 0; it < 4; ++it) {
      int idx = it * 256 + tid;
      int t = idx >> 4;
      int d0 = (idx & 15) << 3;
      *reinterpret_cast<uint4*>(&kb[t][d0]) =
          *reinterpret_cast<const uint4*>(&phiK[kvbase + (size_t)t * DHEAD + d0]);
    }
    // v^T, t < 64 (lane-t mapping: conflict-free LDS writes)
    int t = tid & 63, dp = tid >> 6;
#pragma unroll
    for (int i = 0; i < 4; ++i) {
      int d0 = (dp + 4 * i) * 8;
      uint4 v4 = *reinterpret_cast<const uint4*>(&Vb[kvbase + (size_t)t * DHEAD + d0]);
      const unsigned short* vp = reinterpret_cast<const unsigned short*>(&v4);
#pragma unroll
      for (int j = 0; j < 8; ++j) vt[d0 + j][t] = vp[j];
    }
  } else {
    // k rows 0..127
#pragma unroll
    for (int it = 0; it < 8; ++it) {
      int idx = it * 256 + tid;
      int t = idx >> 4;
      int d0 = (idx & 15) << 3;
      *reinterpret_cast<uint4*>(&kb[t][d0]) =
          *reinterpret_cast<const uint4*>(&phiK[kvbase + (size_t)t * DHEAD + d0]);
    }
    // v^T, t < 128
    int t = tid & 127, dp = tid >> 7;
#pragma unroll
    for (int i = 0; i < 8; ++i) {
      int d0 = (dp + 2 * i) * 8;
      uint4 v4 = *reinterpret_cast<const uint4*>(&Vb[kvbase + (size_t)t * DHEAD + d0]);
      const unsigned short* vp = reinterpret_cast<const unsigned short*>(&v4);
#pragma unroll
      for (int j = 0; j < 8; ++j) vt[d0 + j][t] = vp[j];
    }
  }
  __syncthreads();

  // ---- S = q @ k^T, mask, P -> kb rows 0..63 ----
  if (h == 0) {
    f32x4 sa[4];
#pragma unroll
    for (int i = 0; i < 4; ++i) sa[i] = (f32x4)0.0f;
#pragma unroll
    for (int ks = 0; ks < 4; ++ks) {
      int d0 = ks * 32 + kgrp * 8;
      bf16x8 af = *reinterpret_cast<const bf16x8*>(&qb[wave * 16 + lrow][d0]);
#pragma unroll
      for (int tc = 0; tc < 4; ++tc) {
        bf16x8 bf = *reinterpret_cast<const bf16x8*>(&kb[tc * 16 + lrow][d0]);
        sa[tc] = __builtin_amdgcn_mfma_f32_16x16x32_bf16(af, bf, sa[tc], 0, 0, 0);
      }
    }
    __syncthreads();   // all waves done reading kb as k
#pragma unroll
    for (int tc = 0; tc < 4; ++tc)
#pragma unroll
      for (int r = 0; r < 4; ++r) {
        int trow = wave * 16 + kgrp * 4 + r;
        int s = tc * 16 + lrow;
        kb[trow][s] = f2bf((s <= trow) ? sa[tc][r] : 0.0f);
      }
  } else {
    f32x4 sa[8];
#pragma unroll
    for (int i = 0; i < 8; ++i) sa[i] = (f32x4)0.0f;
#pragma unroll
    for (int ks = 0; ks < 4; ++ks) {
      int d0 = ks * 32 + kgrp * 8;
      bf16x8 af = *reinterpret_cast<const bf16x8*>(&qb[wave * 16 + lrow][d0]);
#pragma unroll
      for (int tc = 0; tc < 8; ++tc) {
        bf16x8 bf = *reinterpret_cast<const bf16x8*>(&kb[tc * 16 + lrow][d0]);
        sa[tc] = __builtin_amdgcn_mfma_f32_16x16x32_bf16(af, bf, sa[tc], 0, 0, 0);
      }
    }
    __syncthreads();
#pragma unroll
    for (int tc = 0; tc < 8; ++tc)
#pragma unroll
      for (int r = 0; r < 4; ++r) {
        int trow = wave * 16 + kgrp * 4 + r;
        int s = tc * 16 + lrow;
        kb[trow][s] = f2bf((s <= 64 + trow) ? sa[tc][r] : 0.0f);
      }
  }
  __syncthreads();   // P visible

  // ---- den = rowsum(P) + q . ks_prefix ----
  {
    int t = tid & 63, h4 = tid >> 6;
    float s = 0.0f;
    if (h4 < 2) {
      if (h4 * 64 < (h + 1) * 64) {
        for (int j = h4 * 64; j < h4 * 64 + 64; ++j) s += bf2f(kb[t][j]);
      }
    } else {
      for (int j = (h4 - 2) * 64; j < (h4 - 2) * 64 + 64; ++j)
        s += bf2f(qb[t][j]) * ks_l[j];
    }
    dsum[h4][t] = s;
  }

  // ---- O = P @ v ----
  f32x4 acc[8];
#pragma unroll
  for (int i = 0; i < 8; ++i) acc[i] = (f32x4)0.0f;
  if (h == 0) {
#pragma unroll
    for (int ks = 0; ks < 2; ++ks) {
      int t0 = ks * 32 + kgrp * 8;
      bf16x8 af = *reinterpret_cast<const bf16x8*>(&kb[wave * 16 + lrow][t0]);
#pragma unroll
      for (int tc = 0; tc < 8; ++tc) {
        bf16x8 bf = *reinterpret_cast<const bf16x8*>(&vt[tc * 16 + lrow][t0]);
        acc[tc] = __builtin_amdgcn_mfma_f32_16x16x32_bf16(af, bf, acc[tc], 0, 0, 0);
      }
    }
  } else {
#pragma unroll
    for (int ks = 0; ks < 4; ++ks) {
      int t0 = ks * 32 + kgrp * 8;
      bf16x8 af = *reinterpret_cast<const bf16x8*>(&kb[wave * 16 + lrow][t0]);
#pragma unroll
      for (int tc = 0; tc < 8; ++tc) {
        bf16x8 bf = *reinterpret_cast<const bf16x8*>(&vt[tc * 16 + lrow][t0]);
        acc[tc] = __builtin_amdgcn_mfma_f32_16x16x32_bf16(af, bf, acc[tc], 0, 0, 0);
      }
    }
  }
  __syncthreads();   // done reading vt (and P); dsum visible after barrier too

  // ---- restage exclusive-prefix KV [dv][d] into vt ----
#pragma unroll
  for (int it = 0; it < 8; ++it) {
    int idx = it * 256 + tid;
    int dv = idx >> 4;
    int d0 = (idx & 15) << 3;
    *reinterpret_cast<uint4*>(&vt[dv][d0]) =
        *reinterpret_cast<const uint4*>(&KVp[(size_t)c * 16384 + (size_t)dv * DHEAD + d0]);
  }
  __syncthreads();

  // ---- O += q @ KV ----
#pragma unroll
  for (int ks = 0; ks < 4; ++ks) {
    int d0 = ks * 32 + kgrp * 8;
    bf16x8 af = *reinterpret_cast<const bf16x8*>(&qb[wave * 16 + lrow][d0]);
#pragma unroll
    for (int tc = 0; tc < 8; ++tc) {
      bf16x8 bf = *reinterpret_cast<const bf16x8*>(&vt[tc * 16 + lrow][d0]);
      acc[tc] = __builtin_amdgcn_mfma_f32_16x16x32_bf16(af, bf, acc[tc], 0, 0, 0);
    }
  }

  // ---- divide + store ----
#pragma unroll
  for (int tc = 0; tc < 8; ++tc)
#pragma unroll
    for (int r = 0; r < 4; ++r) {
      int trow = wave * 16 + kgrp * 4 + r;
      int dv = tc * 16 + lrow;
      float den = dsum[0][trow] + dsum[1][trow] + dsum[2][trow] + dsum[3][trow];
      outp[qbase + (size_t)trow * DHEAD + dv] = acc[tc][r] / den;
    }
}

extern "C" void kernel_launch(void* const* d_in, const int* in_sizes, int n_in,
                              void* d_out, int out_size, void* d_ws, size_t ws_size,
                              hipStream_t stream) {
  const float* x  = (const float*)d_in[0];
  const float* Wq = (const float*)d_in[1];
  const float* Wk = (const float*)d_in[2];
  const float* Wv = (const float*)d_in[3];
  float* out = (float*)d_out;
  char* ws = (char*)d_ws;
  unsigned short* phiQ = (unsigned short*)(ws + 0);          // 4 MB
  unsigned short* phiK = (unsigned short*)(ws + 4194304);    // 4 MB
  unsigned short* Vb   = (unsigned short*)(ws + 8388608);    // 4 MB
  unsigned short* WT   = (unsigned short*)(ws + 12582912);   // 768 KB
  float*          KVc  = (float*)(ws + 13369344);            // 8 MB
  unsigned short* KVp  = (unsigned short*)(ws + 21757952);   // 4 MB
  float*          ksc  = (float*)(ws + 25952256);            // 64 KB
  float*          ksp  = (float*)(ws + 26017792);            // 64 KB

  transpose_w_kernel<<<1536, 256, 0, stream>>>(Wq, Wk, Wv, WT);
  proj_kernel<<<dim3(256, 3), 128, 0, stream>>>(x, WT, phiQ, phiK, Vb);
  chunkkv_kernel<<<128, 256, 0, stream>>>(phiK, Vb, KVc, ksc);
  prefix_kernel<<<257, 256, 0, stream>>>(KVc, ksc, KVp, ksp);
  out_kernel<<<dim3(128, 2), 256, 0, stream>>>(phiQ, phiK, Vb, KVp, ksp, out);
}

// Round 9
// 61.616 us; speedup vs baseline: 1.2525x; 1.2525x over previous
//
#include <hip/hip_runtime.h>

#define DMODEL 1024
#define DHEAD 128
#define CHUNK 128
#define NCHUNK 32

typedef __attribute__((ext_vector_type(4))) float f32x4;
typedef __attribute__((ext_vector_type(8))) short bf16x8;

__device__ __forceinline__ unsigned short f2bf(float f) {
  union { float f; unsigned u; } v; v.f = f;
  unsigned r = v.u + 0x7FFF + ((v.u >> 16) & 1);   // RNE
  return (unsigned short)(r >> 16);
}
__device__ __forceinline__ float bf2f(unsigned short h) {
  union { unsigned u; float f; } v; v.u = ((unsigned)h) << 16;
  return v.f;
}
__device__ __forceinline__ unsigned cvtpk(float lo, float hi) {
  unsigned r;
  asm("v_cvt_pk_bf16_f32 %0, %1, %2" : "=v"(r) : "v"(lo), "v"(hi));
  return r;
}
__device__ __forceinline__ void gload16(const void* g, void* l) {
  __builtin_amdgcn_global_load_lds(
      (const __attribute__((address_space(1))) unsigned int*)g,
      (__attribute__((address_space(3))) unsigned int*)l, 16, 0, 0);
}

// ---------------- K0: W -> W^T bf16 [which][n][k] ----------------
__global__ __launch_bounds__(256) void transpose_w_kernel(
    const float* __restrict__ Wq, const float* __restrict__ Wk,
    const float* __restrict__ Wv, unsigned short* __restrict__ WT) {
  int id = blockIdx.x * 256 + threadIdx.x;
  int w = id >> 17;
  int rem = id & 131071;
  int n = rem >> 10;
  int k = rem & 1023;
  const float* W = (w == 0) ? Wq : (w == 1) ? Wk : Wv;
  WT[id] = f2bf(W[(size_t)k * DHEAD + n]);
}

// ---------------- K1: fused projection GEMM + phi (m97-style) ----------------
// grid (128, 3): BM=128, BN=128, BK=32, 256 threads, 4 waves in 2x2 quadrants.
// Single-buffer LDS (24 KB), two barriers per K-step.
__global__ __launch_bounds__(256) void proj_kernel(
    const float* __restrict__ x, const unsigned short* __restrict__ WT,
    unsigned short* __restrict__ phiQ, unsigned short* __restrict__ phiK,
    unsigned short* __restrict__ Vb) {
  const int which = blockIdx.y;
  const unsigned short* Wt = WT + (size_t)which * (DHEAD * DMODEL);
  unsigned short* outp = (which == 0) ? phiQ : (which == 1) ? phiK : Vb;
  const int m0 = blockIdx.x * 128;

  __shared__ float xs[128][32];            // 16 KB, rows 128B = 8 slots, swizzled
  __shared__ unsigned short ws[128][32];   // 8 KB, rows 64B = 4 slots, swizzled

  const int tid = threadIdx.x;
  const int wave = tid >> 6;
  const int lane = tid & 63;
  const int lrow = lane & 15, kgrp = lane >> 4;
  const int wr = wave >> 1, wc = wave & 1;   // 2x2 wave grid

  f32x4 acc[4][4];
#pragma unroll
  for (int i = 0; i < 4; ++i)
#pragma unroll
    for (int j = 0; j < 4; ++j) acc[i][j] = (f32x4)0.0f;

  for (int kk = 0; kk < DMODEL; kk += 32) {
    if (kk) __syncthreads();               // prior reads done before overwrite
    // stage x tile 128x32 fp32 (16 wave-instrs of 1024B, swizzled source)
#pragma unroll
    for (int i = 0; i < 4; ++i) {
      int instr = i * 4 + wave;
      int row = instr * 8 + (lane >> 3);
      int slot = lane & 7;
      int gcol = (slot ^ (row & 7)) << 2;
      gload16(&x[(size_t)(m0 + row) * DMODEL + kk + gcol],
              (char*)xs + instr * 1024);
    }
    // stage W^T tile 128x32 bf16 (8 wave-instrs)
#pragma unroll
    for (int i = 0; i < 2; ++i) {
      int instr = i * 4 + wave;
      int row = instr * 16 + (lane >> 2);
      int slot = lane & 3;
      int gcol = (slot ^ (row & 3)) << 3;
      gload16(&Wt[(size_t)row * DMODEL + kk + gcol],
              (char*)ws + instr * 1024);
    }
    __syncthreads();                       // drain -> tiles ready

    bf16x8 af[4];
#pragma unroll
    for (int mi = 0; mi < 4; ++mi) {
      int arow = wr * 64 + mi * 16 + lrow;
      int s0 = kgrp * 2;
      const float4 f0 = *reinterpret_cast<const float4*>(
          &xs[arow][(s0 ^ (arow & 7)) << 2]);
      const float4 f1 = *reinterpret_cast<const float4*>(
          &xs[arow][((s0 + 1) ^ (arow & 7)) << 2]);
      union { unsigned u[4]; bf16x8 v; } p;
      p.u[0] = cvtpk(f0.x, f0.y);
      p.u[1] = cvtpk(f0.z, f0.w);
      p.u[2] = cvtpk(f1.x, f1.y);
      p.u[3] = cvtpk(f1.z, f1.w);
      af[mi] = p.v;
    }
#pragma unroll
    for (int ni = 0; ni < 4; ++ni) {
      int brow = wc * 64 + ni * 16 + lrow;
      bf16x8 bf = *reinterpret_cast<const bf16x8*>(
          &ws[brow][(kgrp ^ (brow & 3)) << 3]);
#pragma unroll
      for (int mi = 0; mi < 4; ++mi)
        acc[mi][ni] = __builtin_amdgcn_mfma_f32_16x16x32_bf16(af[mi], bf, acc[mi][ni], 0, 0, 0);
    }
  }
  // epilogue: phi for q/k, plain for v; store bf16
#pragma unroll
  for (int mi = 0; mi < 4; ++mi)
#pragma unroll
    for (int ni = 0; ni < 4; ++ni)
#pragma unroll
      for (int r = 0; r < 4; ++r) {
        int row = m0 + wr * 64 + mi * 16 + kgrp * 4 + r;
        int col = wc * 64 + ni * 16 + lrow;
        float v = acc[mi][ni][r];
        if (which < 2) v = (v > 0.0f) ? (v + 1.0f) : __expf(v);
        outp[(size_t)row * DHEAD + col] = f2bf(v);
      }
}

// ---------------- K2: per-chunk KV^T = v^T @ k, ks colsums ----------------
__global__ __launch_bounds__(256) void chunkkv_kernel(
    const unsigned short* __restrict__ phiK, const unsigned short* __restrict__ Vb,
    float* __restrict__ KVc, float* __restrict__ ksc) {
  const size_t base = (size_t)blockIdx.x * CHUNK * DHEAD;
  __shared__ unsigned short kt[128][136];   // k^T [d][t]
  __shared__ unsigned short vt[128][136];   // v^T [dv][t]
  __shared__ float csum[2][128];
  const int tid = threadIdx.x;
  const int wave = tid >> 6, lane = tid & 63;
  const int lrow = lane & 15, kgrp = lane >> 4;

  // transposed staging: lanes vary t (conflict-free LDS writes)
  {
    int t = tid & 127, dp = tid >> 7;
#pragma unroll
    for (int i = 0; i < 8; ++i) {
      int d0 = (dp + 2 * i) * 8;
      uint4 k4 = *reinterpret_cast<const uint4*>(&phiK[base + (size_t)t * DHEAD + d0]);
      uint4 v4 = *reinterpret_cast<const uint4*>(&Vb[base + (size_t)t * DHEAD + d0]);
      const unsigned short* kp = reinterpret_cast<const unsigned short*>(&k4);
      const unsigned short* vp = reinterpret_cast<const unsigned short*>(&v4);
#pragma unroll
      for (int j = 0; j < 8; ++j) { kt[d0 + j][t] = kp[j]; vt[d0 + j][t] = vp[j]; }
    }
  }
  __syncthreads();

  f32x4 acc[2][8];
#pragma unroll
  for (int i = 0; i < 2; ++i)
#pragma unroll
    for (int j = 0; j < 8; ++j) acc[i][j] = (f32x4)0.0f;
#pragma unroll
  for (int ks = 0; ks < 4; ++ks) {
    int t0 = ks * 32 + kgrp * 8;
    bf16x8 afrag[2];
#pragma unroll
    for (int tr = 0; tr < 2; ++tr)
      afrag[tr] = *reinterpret_cast<const bf16x8*>(&vt[wave * 32 + tr * 16 + lrow][t0]);
#pragma unroll
    for (int tc = 0; tc < 8; ++tc) {
      bf16x8 bfrag = *reinterpret_cast<const bf16x8*>(&kt[tc * 16 + lrow][t0]);
      acc[0][tc] = __builtin_amdgcn_mfma_f32_16x16x32_bf16(afrag[0], bfrag, acc[0][tc], 0, 0, 0);
      acc[1][tc] = __builtin_amdgcn_mfma_f32_16x16x32_bf16(afrag[1], bfrag, acc[1][tc], 0, 0, 0);
    }
  }
  float* KVout = KVc + (size_t)blockIdx.x * (DHEAD * DHEAD);   // [dv][d]
#pragma unroll
  for (int tr = 0; tr < 2; ++tr)
#pragma unroll
    for (int tc = 0; tc < 8; ++tc)
#pragma unroll
      for (int r = 0; r < 4; ++r) {
        int dv = wave * 32 + tr * 16 + kgrp * 4 + r;
        int d = tc * 16 + lrow;
        KVout[dv * DHEAD + d] = acc[tr][tc][r];
      }
  {
    int d = tid & 127, hh = tid >> 7;
    float s = 0.0f;
    for (int t = hh * 64; t < hh * 64 + 64; ++t) s += bf2f(kt[d][t]);
    csum[hh][d] = s;
  }
  __syncthreads();
  if (tid < 128) ksc[(size_t)blockIdx.x * DHEAD + tid] = csum[0][tid] + csum[1][tid];
}

// ---------------- K3: exclusive prefix over chunks ----------------
__global__ __launch_bounds__(256) void prefix_kernel(
    const float* __restrict__ KVc, const float* __restrict__ ksc,
    unsigned short* __restrict__ KVp, float* __restrict__ ksp) {
  if (blockIdx.x < 256) {
    int id = blockIdx.x * 256 + threadIdx.x;
    int b = id >> 14;
    int e = id & 16383;
    size_t base = (size_t)b * NCHUNK * 16384 + e;
    float acc = 0.0f;
    for (int c = 0; c < NCHUNK; ++c) {
      KVp[base + (size_t)c * 16384] = f2bf(acc);
      acc += KVc[base + (size_t)c * 16384];
    }
  } else {
    for (int i = threadIdx.x; i < 512; i += 256) {
      int b = i >> 7, d = i & 127;
      size_t base = (size_t)b * NCHUNK * DHEAD + d;
      float acc = 0.0f;
      for (int c = 0; c < NCHUNK; ++c) {
        ksp[base + (size_t)c * DHEAD] = acc;
        acc += ksc[base + (size_t)c * DHEAD];
      }
    }
  }
}

// ---------------- K4: per-chunk output, split in q-row halves ----------------
// grid (128, 2): blockIdx.x = chunk, blockIdx.y = h (q rows h*64..h*64+63).
__global__ __launch_bounds__(256) void out_kernel(
    const unsigned short* __restrict__ phiQ, const unsigned short* __restrict__ phiK,
    const unsigned short* __restrict__ Vb, const unsigned short* __restrict__ KVp,
    const float* __restrict__ ksp, float* __restrict__ outp) {
  const int c = blockIdx.x;
  const int h = blockIdx.y;
  const size_t kvbase = (size_t)c * CHUNK * DHEAD;
  const size_t qbase = kvbase + (size_t)h * 64 * DHEAD;
  __shared__ unsigned short qb[64][136];    // q rows (this half)
  __shared__ unsigned short kb[128][136];   // k rows; P overwrites rows 0..63
  __shared__ unsigned short vt[128][136];   // v^T [dv][t]; later KV [dv][d]
  __shared__ float dsum[4][64];
  __shared__ float ks_l[128];
  const int tid = threadIdx.x;
  const int wave = tid >> 6, lane = tid & 63;
  const int lrow = lane & 15, kgrp = lane >> 4;

  // stage q (coalesced)
#pragma unroll
  for (int it = 0; it < 4; ++it) {
    int idx = it * 256 + tid;
    int t = idx >> 4;
    int d0 = (idx & 15) << 3;
    *reinterpret_cast<uint4*>(&qb[t][d0]) =
        *reinterpret_cast<const uint4*>(&phiQ[qbase + (size_t)t * DHEAD + d0]);
  }
  if (tid < 128) ks_l[tid] = ksp[(size_t)c * DHEAD + tid];
  if (h == 0) {
#pragma unroll
    for (int it = 0; it < 4; ++it) {
      int idx = it * 256 + tid;
      int t = idx >> 4;
      int d0 = (idx & 15) << 3;
      *reinterpret_cast<uint4*>(&kb[t][d0]) =
          *reinterpret_cast<const uint4*>(&phiK[kvbase + (size_t)t * DHEAD + d0]);
    }
    int t = tid & 63, dp = tid >> 6;
#pragma unroll
    for (int i = 0; i < 4; ++i) {
      int d0 = (dp + 4 * i) * 8;
      uint4 v4 = *reinterpret_cast<const uint4*>(&Vb[kvbase + (size_t)t * DHEAD + d0]);
      const unsigned short* vp = reinterpret_cast<const unsigned short*>(&v4);
#pragma unroll
      for (int j = 0; j < 8; ++j) vt[d0 + j][t] = vp[j];
    }
  } else {
#pragma unroll
    for (int it = 0; it < 8; ++it) {
      int idx = it * 256 + tid;
      int t = idx >> 4;
      int d0 = (idx & 15) << 3;
      *reinterpret_cast<uint4*>(&kb[t][d0]) =
          *reinterpret_cast<const uint4*>(&phiK[kvbase + (size_t)t * DHEAD + d0]);
    }
    int t = tid & 127, dp = tid >> 7;
#pragma unroll
    for (int i = 0; i < 8; ++i) {
      int d0 = (dp + 2 * i) * 8;
      uint4 v4 = *reinterpret_cast<const uint4*>(&Vb[kvbase + (size_t)t * DHEAD + d0]);
      const unsigned short* vp = reinterpret_cast<const unsigned short*>(&v4);
#pragma unroll
      for (int j = 0; j < 8; ++j) vt[d0 + j][t] = vp[j];
    }
  }
  __syncthreads();

  // ---- S = q @ k^T, mask, P -> kb rows 0..63 ----
  if (h == 0) {
    f32x4 sa[4];
#pragma unroll
    for (int i = 0; i < 4; ++i) sa[i] = (f32x4)0.0f;
#pragma unroll
    for (int ks = 0; ks < 4; ++ks) {
      int d0 = ks * 32 + kgrp * 8;
      bf16x8 af = *reinterpret_cast<const bf16x8*>(&qb[wave * 16 + lrow][d0]);
#pragma unroll
      for (int tc = 0; tc < 4; ++tc) {
        bf16x8 bf = *reinterpret_cast<const bf16x8*>(&kb[tc * 16 + lrow][d0]);
        sa[tc] = __builtin_amdgcn_mfma_f32_16x16x32_bf16(af, bf, sa[tc], 0, 0, 0);
      }
    }
    __syncthreads();
#pragma unroll
    for (int tc = 0; tc < 4; ++tc)
#pragma unroll
      for (int r = 0; r < 4; ++r) {
        int trow = wave * 16 + kgrp * 4 + r;
        int s = tc * 16 + lrow;
        kb[trow][s] = f2bf((s <= trow) ? sa[tc][r] : 0.0f);
      }
  } else {
    f32x4 sa[8];
#pragma unroll
    for (int i = 0; i < 8; ++i) sa[i] = (f32x4)0.0f;
#pragma unroll
    for (int ks = 0; ks < 4; ++ks) {
      int d0 = ks * 32 + kgrp * 8;
      bf16x8 af = *reinterpret_cast<const bf16x8*>(&qb[wave * 16 + lrow][d0]);
#pragma unroll
      for (int tc = 0; tc < 8; ++tc) {
        bf16x8 bf = *reinterpret_cast<const bf16x8*>(&kb[tc * 16 + lrow][d0]);
        sa[tc] = __builtin_amdgcn_mfma_f32_16x16x32_bf16(af, bf, sa[tc], 0, 0, 0);
      }
    }
    __syncthreads();
#pragma unroll
    for (int tc = 0; tc < 8; ++tc)
#pragma unroll
      for (int r = 0; r < 4; ++r) {
        int trow = wave * 16 + kgrp * 4 + r;
        int s = tc * 16 + lrow;
        kb[trow][s] = f2bf((s <= 64 + trow) ? sa[tc][r] : 0.0f);
      }
  }
  __syncthreads();   // P visible

  // ---- den = rowsum(P) + q . ks_prefix ----
  {
    int t = tid & 63, h4 = tid >> 6;
    float s = 0.0f;
    if (h4 < 2) {
      if (h4 == 0 || h == 1) {
        for (int j = h4 * 64; j < h4 * 64 + 64; ++j) s += bf2f(kb[t][j]);
      }
    } else {
      for (int j = (h4 - 2) * 64; j < (h4 - 2) * 64 + 64; ++j)
        s += bf2f(qb[t][j]) * ks_l[j];
    }
    dsum[h4][t] = s;
  }

  // ---- O = P @ v ----
  f32x4 acc[8];
#pragma unroll
  for (int i = 0; i < 8; ++i) acc[i] = (f32x4)0.0f;
  {
    const int nks = (h == 0) ? 2 : 4;
    for (int ks = 0; ks < nks; ++ks) {
      int t0 = ks * 32 + kgrp * 8;
      bf16x8 af = *reinterpret_cast<const bf16x8*>(&kb[wave * 16 + lrow][t0]);
#pragma unroll
      for (int tc = 0; tc < 8; ++tc) {
        bf16x8 bf = *reinterpret_cast<const bf16x8*>(&vt[tc * 16 + lrow][t0]);
        acc[tc] = __builtin_amdgcn_mfma_f32_16x16x32_bf16(af, bf, acc[tc], 0, 0, 0);
      }
    }
  }
  __syncthreads();   // done reading vt/P; dsum visible after barrier

  // ---- restage exclusive-prefix KV [dv][d] into vt ----
#pragma unroll
  for (int it = 0; it < 8; ++it) {
    int idx = it * 256 + tid;
    int dv = idx >> 4;
    int d0 = (idx & 15) << 3;
    *reinterpret_cast<uint4*>(&vt[dv][d0]) =
        *reinterpret_cast<const uint4*>(&KVp[(size_t)c * 16384 + (size_t)dv * DHEAD + d0]);
  }
  __syncthreads();

  // ---- O += q @ KV ----
#pragma unroll
  for (int ks = 0; ks < 4; ++ks) {
    int d0 = ks * 32 + kgrp * 8;
    bf16x8 af = *reinterpret_cast<const bf16x8*>(&qb[wave * 16 + lrow][d0]);
#pragma unroll
    for (int tc = 0; tc < 8; ++tc) {
      bf16x8 bf = *reinterpret_cast<const bf16x8*>(&vt[tc * 16 + lrow][d0]);
      acc[tc] = __builtin_amdgcn_mfma_f32_16x16x32_bf16(af, bf, acc[tc], 0, 0, 0);
    }
  }

  // ---- divide + store ----
#pragma unroll
  for (int tc = 0; tc < 8; ++tc)
#pragma unroll
    for (int r = 0; r < 4; ++r) {
      int trow = wave * 16 + kgrp * 4 + r;
      int dv = tc * 16 + lrow;
      float den = dsum[0][trow] + dsum[1][trow] + dsum[2][trow] + dsum[3][trow];
      outp[qbase + (size_t)trow * DHEAD + dv] = acc[tc][r] / den;
    }
}

extern "C" void kernel_launch(void* const* d_in, const int* in_sizes, int n_in,
                              void* d_out, int out_size, void* d_ws, size_t ws_size,
                              hipStream_t stream) {
  const float* x  = (const float*)d_in[0];
  const float* Wq = (const float*)d_in[1];
  const float* Wk = (const float*)d_in[2];
  const float* Wv = (const float*)d_in[3];
  float* out = (float*)d_out;
  char* ws = (char*)d_ws;
  unsigned short* phiQ = (unsigned short*)(ws + 0);          // 4 MB
  unsigned short* phiK = (unsigned short*)(ws + 4194304);    // 4 MB
  unsigned short* Vb   = (unsigned short*)(ws + 8388608);    // 4 MB
  unsigned short* WT   = (unsigned short*)(ws + 12582912);   // 768 KB
  float*          KVc  = (float*)(ws + 13369344);            // 8 MB
  unsigned short* KVp  = (unsigned short*)(ws + 21757952);   // 4 MB
  float*          ksc  = (float*)(ws + 25952256);            // 64 KB
  float*          ksp  = (float*)(ws + 26017792);            // 64 KB

  transpose_w_kernel<<<1536, 256, 0, stream>>>(Wq, Wk, Wv, WT);
  proj_kernel<<<dim3(128, 3), 256, 0, stream>>>(x, WT, phiQ, phiK, Vb);
  chunkkv_kernel<<<128, 256, 0, stream>>>(phiK, Vb, KVc, ksc);
  prefix_kernel<<<257, 256, 0, stream>>>(KVc, ksc, KVp, ksp);
  out_kernel<<<dim3(128, 2), 256, 0, stream>>>(phiQ, phiK, Vb, KVp, ksp, out);
}

// Round 10
// 57.650 us; speedup vs baseline: 1.3387x; 1.0688x over previous
//
#include <hip/hip_runtime.h>

#define DMODEL 1024
#define DHEAD 128
#define CHUNK 128
#define NCHUNK 32

typedef __attribute__((ext_vector_type(4))) float f32x4;
typedef __attribute__((ext_vector_type(8))) short bf16x8;

__device__ __forceinline__ unsigned short f2bf(float f) {
  union { float f; unsigned u; } v; v.f = f;
  unsigned r = v.u + 0x7FFF + ((v.u >> 16) & 1);   // RNE
  return (unsigned short)(r >> 16);
}
__device__ __forceinline__ float bf2f(unsigned short h) {
  union { unsigned u; float f; } v; v.u = ((unsigned)h) << 16;
  return v.f;
}
__device__ __forceinline__ unsigned cvtpk(float lo, float hi) {
  unsigned r;
  asm("v_cvt_pk_bf16_f32 %0, %1, %2" : "=v"(r) : "v"(lo), "v"(hi));
  return r;
}
__device__ __forceinline__ void gload16(const void* g, void* l) {
  __builtin_amdgcn_global_load_lds(
      (const __attribute__((address_space(1))) unsigned int*)g,
      (__attribute__((address_space(3))) unsigned int*)l, 16, 0, 0);
}

// ---------------- K0: W -> W^T bf16 [which][n][k] ----------------
__global__ __launch_bounds__(256) void transpose_w_kernel(
    const float* __restrict__ Wq, const float* __restrict__ Wk,
    const float* __restrict__ Wv, unsigned short* __restrict__ WT) {
  int id = blockIdx.x * 256 + threadIdx.x;
  int w = id >> 17;
  int rem = id & 131071;
  int n = rem >> 10;
  int k = rem & 1023;
  const float* W = (w == 0) ? Wq : (w == 1) ? Wk : Wv;
  WT[id] = f2bf(W[(size_t)k * DHEAD + n]);
}

// ---------------- K1: FUSED projection GEMM + phi ----------------
// grid (256, 2): BM=64 rows, BN=64 cols (n-split), BK=64, 256 threads (4 waves).
// One x-tile staged per step feeds q,k,v GEMMs (3x MFMA per staged byte).
__global__ __launch_bounds__(256) void proj_kernel(
    const float* __restrict__ x, const unsigned short* __restrict__ WT,
    unsigned short* __restrict__ phiQ, unsigned short* __restrict__ phiK,
    unsigned short* __restrict__ Vb) {
  const int m0 = blockIdx.x * 64;
  const int n0 = blockIdx.y * 64;

  __shared__ float xs[64][64];              // 16 KB, 256B rows = 16 slots, swizzled
  __shared__ unsigned short wl[3][64][64];  // 24 KB, 128B rows = 8 slots, swizzled

  const int tid = threadIdx.x;
  const int wave = tid >> 6;                // 0..3, owns rows wave*16..+16
  const int lane = tid & 63;
  const int lrow = lane & 15, kgrp = lane >> 4;

  f32x4 acc[3][4];
#pragma unroll
  for (int w3 = 0; w3 < 3; ++w3)
#pragma unroll
    for (int j = 0; j < 4; ++j) acc[w3][j] = (f32x4)0.0f;

  for (int kk = 0; kk < DMODEL; kk += 64) {
    if (kk) __syncthreads();               // readers done before overwrite
    // stage x tile 64x64 fp32: 16 instrs of 1 KB (4 rows of 256B each)
#pragma unroll
    for (int i = 0; i < 4; ++i) {
      int instr = i * 4 + wave;
      int row = instr * 4 + (lane >> 4);
      int slot = lane & 15;
      int gcol = (slot ^ (row & 7)) << 2;
      gload16(&x[(size_t)(m0 + row) * DMODEL + kk + gcol],
              (char*)xs + instr * 1024);
    }
    // stage Wq/Wk/Wv tiles 64x64 bf16 each: 24 instrs of 1 KB (8 rows of 128B)
#pragma unroll
    for (int i = 0; i < 6; ++i) {
      int j = i * 4 + wave;
      int w3 = j >> 3;
      int jj = j & 7;
      int row = jj * 8 + (lane >> 3);
      int slot = lane & 7;
      int gcol = (slot ^ (row & 7)) << 3;
      gload16(&WT[(size_t)w3 * (DHEAD * DMODEL) + (size_t)(n0 + row) * DMODEL + kk + gcol],
              (char*)wl + w3 * 8192 + jj * 1024);
    }
    __syncthreads();                       // drain -> tiles ready

#pragma unroll
    for (int ks2 = 0; ks2 < 2; ++ks2) {
      // A-fragment (shared across the 3 outputs)
      int arow = wave * 16 + lrow;
      int s0 = ks2 * 8 + kgrp * 2;
      const float4 f0 = *reinterpret_cast<const float4*>(
          &xs[arow][(s0 ^ (arow & 7)) << 2]);
      const float4 f1 = *reinterpret_cast<const float4*>(
          &xs[arow][((s0 + 1) ^ (arow & 7)) << 2]);
      union { unsigned u[4]; bf16x8 v; } p;
      p.u[0] = cvtpk(f0.x, f0.y);
      p.u[1] = cvtpk(f0.z, f0.w);
      p.u[2] = cvtpk(f1.x, f1.y);
      p.u[3] = cvtpk(f1.z, f1.w);
      bf16x8 af = p.v;
#pragma unroll
      for (int w3 = 0; w3 < 3; ++w3)
#pragma unroll
        for (int nt = 0; nt < 4; ++nt) {
          int brow = nt * 16 + lrow;
          int bs = ks2 * 4 + kgrp;
          bf16x8 bf = *reinterpret_cast<const bf16x8*>(
              &wl[w3][brow][(bs ^ (brow & 7)) << 3]);
          acc[w3][nt] = __builtin_amdgcn_mfma_f32_16x16x32_bf16(af, bf, acc[w3][nt], 0, 0, 0);
        }
    }
  }
  // epilogue: phi for q/k, plain for v; store bf16
#pragma unroll
  for (int w3 = 0; w3 < 3; ++w3) {
    unsigned short* outp = (w3 == 0) ? phiQ : (w3 == 1) ? phiK : Vb;
#pragma unroll
    for (int nt = 0; nt < 4; ++nt)
#pragma unroll
      for (int r = 0; r < 4; ++r) {
        int row = m0 + wave * 16 + kgrp * 4 + r;
        int col = n0 + nt * 16 + lrow;
        float v = acc[w3][nt][r];
        if (w3 < 2) v = (v > 0.0f) ? (v + 1.0f) : __expf(v);
        outp[(size_t)row * DHEAD + col] = f2bf(v);
      }
  }
}

// ---------------- K2: per-chunk KV^T = v^T @ k, ks colsums ----------------
__global__ __launch_bounds__(256) void chunkkv_kernel(
    const unsigned short* __restrict__ phiK, const unsigned short* __restrict__ Vb,
    float* __restrict__ KVc, float* __restrict__ ksc) {
  const size_t base = (size_t)blockIdx.x * CHUNK * DHEAD;
  __shared__ unsigned short kt[128][136];   // k^T [d][t]
  __shared__ unsigned short vt[128][136];   // v^T [dv][t]
  __shared__ float csum[2][128];
  const int tid = threadIdx.x;
  const int wave = tid >> 6, lane = tid & 63;
  const int lrow = lane & 15, kgrp = lane >> 4;

  {
    int t = tid & 127, dp = tid >> 7;
#pragma unroll
    for (int i = 0; i < 8; ++i) {
      int d0 = (dp + 2 * i) * 8;
      uint4 k4 = *reinterpret_cast<const uint4*>(&phiK[base + (size_t)t * DHEAD + d0]);
      uint4 v4 = *reinterpret_cast<const uint4*>(&Vb[base + (size_t)t * DHEAD + d0]);
      const unsigned short* kp = reinterpret_cast<const unsigned short*>(&k4);
      const unsigned short* vp = reinterpret_cast<const unsigned short*>(&v4);
#pragma unroll
      for (int j = 0; j < 8; ++j) { kt[d0 + j][t] = kp[j]; vt[d0 + j][t] = vp[j]; }
    }
  }
  __syncthreads();

  f32x4 acc[2][8];
#pragma unroll
  for (int i = 0; i < 2; ++i)
#pragma unroll
    for (int j = 0; j < 8; ++j) acc[i][j] = (f32x4)0.0f;
#pragma unroll
  for (int ks = 0; ks < 4; ++ks) {
    int t0 = ks * 32 + kgrp * 8;
    bf16x8 afrag[2];
#pragma unroll
    for (int tr = 0; tr < 2; ++tr)
      afrag[tr] = *reinterpret_cast<const bf16x8*>(&vt[wave * 32 + tr * 16 + lrow][t0]);
#pragma unroll
    for (int tc = 0; tc < 8; ++tc) {
      bf16x8 bfrag = *reinterpret_cast<const bf16x8*>(&kt[tc * 16 + lrow][t0]);
      acc[0][tc] = __builtin_amdgcn_mfma_f32_16x16x32_bf16(afrag[0], bfrag, acc[0][tc], 0, 0, 0);
      acc[1][tc] = __builtin_amdgcn_mfma_f32_16x16x32_bf16(afrag[1], bfrag, acc[1][tc], 0, 0, 0);
    }
  }
  float* KVout = KVc + (size_t)blockIdx.x * (DHEAD * DHEAD);   // [dv][d]
#pragma unroll
  for (int tr = 0; tr < 2; ++tr)
#pragma unroll
    for (int tc = 0; tc < 8; ++tc)
#pragma unroll
      for (int r = 0; r < 4; ++r) {
        int dv = wave * 32 + tr * 16 + kgrp * 4 + r;
        int d = tc * 16 + lrow;
        KVout[dv * DHEAD + d] = acc[tr][tc][r];
      }
  {
    int d = tid & 127, hh = tid >> 7;
    float s = 0.0f;
    for (int t = hh * 64; t < hh * 64 + 64; ++t) s += bf2f(kt[d][t]);
    csum[hh][d] = s;
  }
  __syncthreads();
  if (tid < 128) ksc[(size_t)blockIdx.x * DHEAD + tid] = csum[0][tid] + csum[1][tid];
}

// ---------------- K3: exclusive prefix over chunks ----------------
__global__ __launch_bounds__(256) void prefix_kernel(
    const float* __restrict__ KVc, const float* __restrict__ ksc,
    unsigned short* __restrict__ KVp, float* __restrict__ ksp) {
  if (blockIdx.x < 256) {
    int id = blockIdx.x * 256 + threadIdx.x;
    int b = id >> 14;
    int e = id & 16383;
    size_t base = (size_t)b * NCHUNK * 16384 + e;
    float acc = 0.0f;
    for (int c = 0; c < NCHUNK; ++c) {
      KVp[base + (size_t)c * 16384] = f2bf(acc);
      acc += KVc[base + (size_t)c * 16384];
    }
  } else {
    for (int i = threadIdx.x; i < 512; i += 256) {
      int b = i >> 7, d = i & 127;
      size_t base = (size_t)b * NCHUNK * DHEAD + d;
      float acc = 0.0f;
      for (int c = 0; c < NCHUNK; ++c) {
        ksp[base + (size_t)c * DHEAD] = acc;
        acc += ksc[base + (size_t)c * DHEAD];
      }
    }
  }
}

// ---------------- K4: per-chunk output, split in q-row halves ----------------
__global__ __launch_bounds__(256) void out_kernel(
    const unsigned short* __restrict__ phiQ, const unsigned short* __restrict__ phiK,
    const unsigned short* __restrict__ Vb, const unsigned short* __restrict__ KVp,
    const float* __restrict__ ksp, float* __restrict__ outp) {
  const int c = blockIdx.x;
  const int h = blockIdx.y;
  const size_t kvbase = (size_t)c * CHUNK * DHEAD;
  const size_t qbase = kvbase + (size_t)h * 64 * DHEAD;
  __shared__ unsigned short qb[64][136];
  __shared__ unsigned short kb[128][136];
  __shared__ unsigned short vt[128][136];
  __shared__ float dsum[4][64];
  __shared__ float ks_l[128];
  const int tid = threadIdx.x;
  const int wave = tid >> 6, lane = tid & 63;
  const int lrow = lane & 15, kgrp = lane >> 4;

#pragma unroll
  for (int it = 0; it < 4; ++it) {
    int idx = it * 256 + tid;
    int t = idx >> 4;
    int d0 = (idx & 15) << 3;
    *reinterpret_cast<uint4*>(&qb[t][d0]) =
        *reinterpret_cast<const uint4*>(&phiQ[qbase + (size_t)t * DHEAD + d0]);
  }
  if (tid < 128) ks_l[tid] = ksp[(size_t)c * DHEAD + tid];
  if (h == 0) {
#pragma unroll
    for (int it = 0; it < 4; ++it) {
      int idx = it * 256 + tid;
      int t = idx >> 4;
      int d0 = (idx & 15) << 3;
      *reinterpret_cast<uint4*>(&kb[t][d0]) =
          *reinterpret_cast<const uint4*>(&phiK[kvbase + (size_t)t * DHEAD + d0]);
    }
    int t = tid & 63, dp = tid >> 6;
#pragma unroll
    for (int i = 0; i < 4; ++i) {
      int d0 = (dp + 4 * i) * 8;
      uint4 v4 = *reinterpret_cast<const uint4*>(&Vb[kvbase + (size_t)t * DHEAD + d0]);
      const unsigned short* vp = reinterpret_cast<const unsigned short*>(&v4);
#pragma unroll
      for (int j = 0; j < 8; ++j) vt[d0 + j][t] = vp[j];
    }
  } else {
#pragma unroll
    for (int it = 0; it < 8; ++it) {
      int idx = it * 256 + tid;
      int t = idx >> 4;
      int d0 = (idx & 15) << 3;
      *reinterpret_cast<uint4*>(&kb[t][d0]) =
          *reinterpret_cast<const uint4*>(&phiK[kvbase + (size_t)t * DHEAD + d0]);
    }
    int t = tid & 127, dp = tid >> 7;
#pragma unroll
    for (int i = 0; i < 8; ++i) {
      int d0 = (dp + 2 * i) * 8;
      uint4 v4 = *reinterpret_cast<const uint4*>(&Vb[kvbase + (size_t)t * DHEAD + d0]);
      const unsigned short* vp = reinterpret_cast<const unsigned short*>(&v4);
#pragma unroll
      for (int j = 0; j < 8; ++j) vt[d0 + j][t] = vp[j];
    }
  }
  __syncthreads();

  if (h == 0) {
    f32x4 sa[4];
#pragma unroll
    for (int i = 0; i < 4; ++i) sa[i] = (f32x4)0.0f;
#pragma unroll
    for (int ks = 0; ks < 4; ++ks) {
      int d0 = ks * 32 + kgrp * 8;
      bf16x8 af = *reinterpret_cast<const bf16x8*>(&qb[wave * 16 + lrow][d0]);
#pragma unroll
      for (int tc = 0; tc < 4; ++tc) {
        bf16x8 bf = *reinterpret_cast<const bf16x8*>(&kb[tc * 16 + lrow][d0]);
        sa[tc] = __builtin_amdgcn_mfma_f32_16x16x32_bf16(af, bf, sa[tc], 0, 0, 0);
      }
    }
    __syncthreads();
#pragma unroll
    for (int tc = 0; tc < 4; ++tc)
#pragma unroll
      for (int r = 0; r < 4; ++r) {
        int trow = wave * 16 + kgrp * 4 + r;
        int s = tc * 16 + lrow;
        kb[trow][s] = f2bf((s <= trow) ? sa[tc][r] : 0.0f);
      }
  } else {
    f32x4 sa[8];
#pragma unroll
    for (int i = 0; i < 8; ++i) sa[i] = (f32x4)0.0f;
#pragma unroll
    for (int ks = 0; ks < 4; ++ks) {
      int d0 = ks * 32 + kgrp * 8;
      bf16x8 af = *reinterpret_cast<const bf16x8*>(&qb[wave * 16 + lrow][d0]);
#pragma unroll
      for (int tc = 0; tc < 8; ++tc) {
        bf16x8 bf = *reinterpret_cast<const bf16x8*>(&kb[tc * 16 + lrow][d0]);
        sa[tc] = __builtin_amdgcn_mfma_f32_16x16x32_bf16(af, bf, sa[tc], 0, 0, 0);
      }
    }
    __syncthreads();
#pragma unroll
    for (int tc = 0; tc < 8; ++tc)
#pragma unroll
      for (int r = 0; r < 4; ++r) {
        int trow = wave * 16 + kgrp * 4 + r;
        int s = tc * 16 + lrow;
        kb[trow][s] = f2bf((s <= 64 + trow) ? sa[tc][r] : 0.0f);
      }
  }
  __syncthreads();   // P visible

  {
    int t = tid & 63, h4 = tid >> 6;
    float s = 0.0f;
    if (h4 < 2) {
      if (h4 == 0 || h == 1) {
        for (int j = h4 * 64; j < h4 * 64 + 64; ++j) s += bf2f(kb[t][j]);
      }
    } else {
      for (int j = (h4 - 2) * 64; j < (h4 - 2) * 64 + 64; ++j)
        s += bf2f(qb[t][j]) * ks_l[j];
    }
    dsum[h4][t] = s;
  }

  f32x4 acc[8];
#pragma unroll
  for (int i = 0; i < 8; ++i) acc[i] = (f32x4)0.0f;
  {
    const int nks = (h == 0) ? 2 : 4;
    for (int ks = 0; ks < nks; ++ks) {
      int t0 = ks * 32 + kgrp * 8;
      bf16x8 af = *reinterpret_cast<const bf16x8*>(&kb[wave * 16 + lrow][t0]);
#pragma unroll
      for (int tc = 0; tc < 8; ++tc) {
        bf16x8 bf = *reinterpret_cast<const bf16x8*>(&vt[tc * 16 + lrow][t0]);
        acc[tc] = __builtin_amdgcn_mfma_f32_16x16x32_bf16(af, bf, acc[tc], 0, 0, 0);
      }
    }
  }
  __syncthreads();

#pragma unroll
  for (int it = 0; it < 8; ++it) {
    int idx = it * 256 + tid;
    int dv = idx >> 4;
    int d0 = (idx & 15) << 3;
    *reinterpret_cast<uint4*>(&vt[dv][d0]) =
        *reinterpret_cast<const uint4*>(&KVp[(size_t)c * 16384 + (size_t)dv * DHEAD + d0]);
  }
  __syncthreads();

#pragma unroll
  for (int ks = 0; ks < 4; ++ks) {
    int d0 = ks * 32 + kgrp * 8;
    bf16x8 af = *reinterpret_cast<const bf16x8*>(&qb[wave * 16 + lrow][d0]);
#pragma unroll
    for (int tc = 0; tc < 8; ++tc) {
      bf16x8 bf = *reinterpret_cast<const bf16x8*>(&vt[tc * 16 + lrow][d0]);
      acc[tc] = __builtin_amdgcn_mfma_f32_16x16x32_bf16(af, bf, acc[tc], 0, 0, 0);
    }
  }

#pragma unroll
  for (int tc = 0; tc < 8; ++tc)
#pragma unroll
    for (int r = 0; r < 4; ++r) {
      int trow = wave * 16 + kgrp * 4 + r;
      int dv = tc * 16 + lrow;
      float den = dsum[0][trow] + dsum[1][trow] + dsum[2][trow] + dsum[3][trow];
      outp[qbase + (size_t)trow * DHEAD + dv] = acc[tc][r] / den;
    }
}

extern "C" void kernel_launch(void* const* d_in, const int* in_sizes, int n_in,
                              void* d_out, int out_size, void* d_ws, size_t ws_size,
                              hipStream_t stream) {
  const float* x  = (const float*)d_in[0];
  const float* Wq = (const float*)d_in[1];
  const float* Wk = (const float*)d_in[2];
  const float* Wv = (const float*)d_in[3];
  float* out = (float*)d_out;
  char* ws = (char*)d_ws;
  unsigned short* phiQ = (unsigned short*)(ws + 0);          // 4 MB
  unsigned short* phiK = (unsigned short*)(ws + 4194304);    // 4 MB
  unsigned short* Vb   = (unsigned short*)(ws + 8388608);    // 4 MB
  unsigned short* WT   = (unsigned short*)(ws + 12582912);   // 768 KB
  float*          KVc  = (float*)(ws + 13369344);            // 8 MB
  unsigned short* KVp  = (unsigned short*)(ws + 21757952);   // 4 MB
  float*          ksc  = (float*)(ws + 25952256);            // 64 KB
  float*          ksp  = (float*)(ws + 26017792);            // 64 KB

  transpose_w_kernel<<<1536, 256, 0, stream>>>(Wq, Wk, Wv, WT);
  proj_kernel<<<dim3(256, 2), 256, 0, stream>>>(x, WT, phiQ, phiK, Vb);
  chunkkv_kernel<<<128, 256, 0, stream>>>(phiK, Vb, KVc, ksc);
  prefix_kernel<<<257, 256, 0, stream>>>(KVc, ksc, KVp, ksp);
  out_kernel<<<dim3(128, 2), 256, 0, stream>>>(phiQ, phiK, Vb, KVp, ksp, out);
}

// Round 11
// 55.547 us; speedup vs baseline: 1.3894x; 1.0379x over previous
//
#include <hip/hip_runtime.h>

#define DMODEL 1024
#define DHEAD 128
#define CHUNK 128
#define NCHUNK 32

typedef __attribute__((ext_vector_type(4))) float f32x4;
typedef __attribute__((ext_vector_type(8))) short bf16x8;

__device__ __forceinline__ unsigned short f2bf(float f) {
  union { float f; unsigned u; } v; v.f = f;
  unsigned r = v.u + 0x7FFF + ((v.u >> 16) & 1);   // RNE
  return (unsigned short)(r >> 16);
}
__device__ __forceinline__ float bf2f(unsigned short h) {
  union { unsigned u; float f; } v; v.u = ((unsigned)h) << 16;
  return v.f;
}
__device__ __forceinline__ unsigned cvtpk(float lo, float hi) {
  unsigned r;
  asm("v_cvt_pk_bf16_f32 %0, %1, %2" : "=v"(r) : "v"(lo), "v"(hi));
  return r;
}
__device__ __forceinline__ void gload16(const void* g, void* l) {
  __builtin_amdgcn_global_load_lds(
      (const __attribute__((address_space(1))) unsigned int*)g,
      (__attribute__((address_space(3))) unsigned int*)l, 16, 0, 0);
}

// ---------------- K0: W -> W^T bf16 [which][n][k] ----------------
__global__ __launch_bounds__(256) void transpose_w_kernel(
    const float* __restrict__ Wq, const float* __restrict__ Wk,
    const float* __restrict__ Wv, unsigned short* __restrict__ WT) {
  int id = blockIdx.x * 256 + threadIdx.x;
  int w = id >> 17;
  int rem = id & 131071;
  int n = rem >> 10;
  int k = rem & 1023;
  const float* W = (w == 0) ? Wq : (w == 1) ? Wk : Wv;
  WT[id] = f2bf(W[(size_t)k * DHEAD + n]);
}

// ---------------- K1: FUSED projection GEMM + phi ----------------
// 1024 blocks: BM=32, BN=64 (n-split 2), BK=64, 256 threads (4 waves).
// XCD-aware decode keeps both n-halves of an m-tile on one XCD (x L2-shared).
__global__ __launch_bounds__(256) void proj_kernel(
    const float* __restrict__ x, const unsigned short* __restrict__ WT,
    unsigned short* __restrict__ phiQ, unsigned short* __restrict__ phiK,
    unsigned short* __restrict__ Vb) {
  const int bid = blockIdx.x;
  const int xcd = bid & 7;
  const int slot = bid >> 3;                 // 0..127
  const int n0 = (slot & 1) << 6;            // 0 or 64
  const int m0 = ((xcd << 6) | (slot >> 1)) << 5;   // 512 m-tiles of 32 rows

  __shared__ float xs[32][64];               // 8 KB, 256B rows, swizzled
  __shared__ unsigned short wl[3][64][64];   // 24 KB, 128B rows, swizzled

  const int tid = threadIdx.x;
  const int wave = tid >> 6;                 // owns n-tile `wave`
  const int lane = tid & 63;
  const int lrow = lane & 15, kgrp = lane >> 4;

  f32x4 acc[3][2];
#pragma unroll
  for (int w3 = 0; w3 < 3; ++w3)
#pragma unroll
    for (int mi = 0; mi < 2; ++mi) acc[w3][mi] = (f32x4)0.0f;

  for (int kk = 0; kk < DMODEL; kk += 64) {
    if (kk) __syncthreads();                 // readers done before overwrite
    // stage x tile 32x64 fp32: 8 instrs of 1 KB (4 rows of 256B)
#pragma unroll
    for (int i = 0; i < 2; ++i) {
      int instr = i * 4 + wave;
      int row = instr * 4 + (lane >> 4);
      int slotc = lane & 15;
      int gcol = (slotc ^ (row & 7)) << 2;
      gload16(&x[(size_t)(m0 + row) * DMODEL + kk + gcol],
              (char*)xs + instr * 1024);
    }
    // stage Wq/Wk/Wv tiles 64x64 bf16: 24 instrs of 1 KB (8 rows of 128B)
#pragma unroll
    for (int i = 0; i < 6; ++i) {
      int j = i * 4 + wave;
      int w3 = j >> 3;
      int jj = j & 7;
      int row = jj * 8 + (lane >> 3);
      int slotc = lane & 7;
      int gcol = (slotc ^ (row & 7)) << 3;
      gload16(&WT[(size_t)w3 * (DHEAD * DMODEL) + (size_t)(n0 + row) * DMODEL + kk + gcol],
              (char*)wl + w3 * 8192 + jj * 1024);
    }
    __syncthreads();                         // drain -> tiles ready

#pragma unroll
    for (int ks2 = 0; ks2 < 2; ++ks2) {
      bf16x8 af[2];
#pragma unroll
      for (int mi = 0; mi < 2; ++mi) {
        int arow = mi * 16 + lrow;
        int s0 = ks2 * 8 + kgrp * 2;
        const float4 f0 = *reinterpret_cast<const float4*>(
            &xs[arow][(s0 ^ (arow & 7)) << 2]);
        const float4 f1 = *reinterpret_cast<const float4*>(
            &xs[arow][((s0 + 1) ^ (arow & 7)) << 2]);
        union { unsigned u[4]; bf16x8 v; } p;
        p.u[0] = cvtpk(f0.x, f0.y);
        p.u[1] = cvtpk(f0.z, f0.w);
        p.u[2] = cvtpk(f1.x, f1.y);
        p.u[3] = cvtpk(f1.z, f1.w);
        af[mi] = p.v;
      }
#pragma unroll
      for (int w3 = 0; w3 < 3; ++w3) {
        int brow = wave * 16 + lrow;
        int bs = ks2 * 4 + kgrp;
        bf16x8 bf = *reinterpret_cast<const bf16x8*>(
            &wl[w3][brow][(bs ^ (brow & 7)) << 3]);
#pragma unroll
        for (int mi = 0; mi < 2; ++mi)
          acc[w3][mi] = __builtin_amdgcn_mfma_f32_16x16x32_bf16(af[mi], bf, acc[w3][mi], 0, 0, 0);
      }
    }
  }
  // epilogue: phi for q/k, plain for v; store bf16
#pragma unroll
  for (int w3 = 0; w3 < 3; ++w3) {
    unsigned short* outp = (w3 == 0) ? phiQ : (w3 == 1) ? phiK : Vb;
#pragma unroll
    for (int mi = 0; mi < 2; ++mi)
#pragma unroll
      for (int r = 0; r < 4; ++r) {
        int row = m0 + mi * 16 + kgrp * 4 + r;
        int col = n0 + wave * 16 + lrow;
        float v = acc[w3][mi][r];
        if (w3 < 2) v = (v > 0.0f) ? (v + 1.0f) : __expf(v);
        outp[(size_t)row * DHEAD + col] = f2bf(v);
      }
  }
}

// ---------------- K2: per-chunk KV^T = v^T @ k (dv-split), ks colsums ----------------
// grid (128, 2): blockIdx.y = dv half.
__global__ __launch_bounds__(256) void chunkkv_kernel(
    const unsigned short* __restrict__ phiK, const unsigned short* __restrict__ Vb,
    float* __restrict__ KVc, float* __restrict__ ksc) {
  const int c = blockIdx.x;
  const int yv = blockIdx.y;
  const size_t base = (size_t)c * CHUNK * DHEAD;
  __shared__ unsigned short kt[128][136];   // k^T [d][t] (full)
  __shared__ unsigned short vt[64][136];    // v^T rows yv*64..+64
  __shared__ float csum[2][128];
  const int tid = threadIdx.x;
  const int wave = tid >> 6, lane = tid & 63;
  const int lrow = lane & 15, kgrp = lane >> 4;

  {
    int t = tid & 127, dp = tid >> 7;
#pragma unroll
    for (int i = 0; i < 8; ++i) {
      int d0 = (dp + 2 * i) * 8;
      uint4 k4 = *reinterpret_cast<const uint4*>(&phiK[base + (size_t)t * DHEAD + d0]);
      const unsigned short* kp = reinterpret_cast<const unsigned short*>(&k4);
#pragma unroll
      for (int j = 0; j < 8; ++j) kt[d0 + j][t] = kp[j];
    }
#pragma unroll
    for (int i = 0; i < 4; ++i) {
      int dl = (dp + 2 * i) * 8;             // 0..63 local dv
      uint4 v4 = *reinterpret_cast<const uint4*>(
          &Vb[base + (size_t)t * DHEAD + yv * 64 + dl]);
      const unsigned short* vp = reinterpret_cast<const unsigned short*>(&v4);
#pragma unroll
      for (int j = 0; j < 8; ++j) vt[dl + j][t] = vp[j];
    }
  }
  __syncthreads();

  f32x4 acc[8];
#pragma unroll
  for (int j = 0; j < 8; ++j) acc[j] = (f32x4)0.0f;
#pragma unroll
  for (int ks = 0; ks < 4; ++ks) {
    int t0 = ks * 32 + kgrp * 8;
    bf16x8 afrag = *reinterpret_cast<const bf16x8*>(&vt[wave * 16 + lrow][t0]);
#pragma unroll
    for (int tc = 0; tc < 8; ++tc) {
      bf16x8 bfrag = *reinterpret_cast<const bf16x8*>(&kt[tc * 16 + lrow][t0]);
      acc[tc] = __builtin_amdgcn_mfma_f32_16x16x32_bf16(afrag, bfrag, acc[tc], 0, 0, 0);
    }
  }
  float* KVout = KVc + (size_t)c * (DHEAD * DHEAD);   // [dv][d]
#pragma unroll
  for (int tc = 0; tc < 8; ++tc)
#pragma unroll
    for (int r = 0; r < 4; ++r) {
      int dv = yv * 64 + wave * 16 + kgrp * 4 + r;
      int d = tc * 16 + lrow;
      KVout[dv * DHEAD + d] = acc[tc][r];
    }
  if (yv == 0) {
    int d = tid & 127, hh = tid >> 7;
    float s = 0.0f;
    for (int t = hh * 64; t < hh * 64 + 64; ++t) s += bf2f(kt[d][t]);
    csum[hh][d] = s;
    __syncthreads();
    if (tid < 128) ksc[(size_t)c * DHEAD + tid] = csum[0][tid] + csum[1][tid];
  }
}

// ---------------- K3: exclusive prefix over chunks ----------------
__global__ __launch_bounds__(256) void prefix_kernel(
    const float* __restrict__ KVc, const float* __restrict__ ksc,
    unsigned short* __restrict__ KVp, float* __restrict__ ksp) {
  if (blockIdx.x < 256) {
    int id = blockIdx.x * 256 + threadIdx.x;
    int b = id >> 14;
    int e = id & 16383;
    size_t base = (size_t)b * NCHUNK * 16384 + e;
    float acc = 0.0f;
    for (int c = 0; c < NCHUNK; ++c) {
      KVp[base + (size_t)c * 16384] = f2bf(acc);
      acc += KVc[base + (size_t)c * 16384];
    }
  } else {
    for (int i = threadIdx.x; i < 512; i += 256) {
      int b = i >> 7, d = i & 127;
      size_t base = (size_t)b * NCHUNK * DHEAD + d;
      float acc = 0.0f;
      for (int c = 0; c < NCHUNK; ++c) {
        ksp[base + (size_t)c * DHEAD] = acc;
        acc += ksc[base + (size_t)c * DHEAD];
      }
    }
  }
}

// ---------------- K4: per-chunk output, split in q-row halves ----------------
__global__ __launch_bounds__(256) void out_kernel(
    const unsigned short* __restrict__ phiQ, const unsigned short* __restrict__ phiK,
    const unsigned short* __restrict__ Vb, const unsigned short* __restrict__ KVp,
    const float* __restrict__ ksp, float* __restrict__ outp) {
  const int c = blockIdx.x;
  const int h = blockIdx.y;
  const size_t kvbase = (size_t)c * CHUNK * DHEAD;
  const size_t qbase = kvbase + (size_t)h * 64 * DHEAD;
  __shared__ unsigned short qb[64][136];
  __shared__ unsigned short kb[128][136];
  __shared__ unsigned short vt[128][136];
  __shared__ float dsum[4][64];
  __shared__ float ks_l[128];
  const int tid = threadIdx.x;
  const int wave = tid >> 6, lane = tid & 63;
  const int lrow = lane & 15, kgrp = lane >> 4;

#pragma unroll
  for (int it = 0; it < 4; ++it) {
    int idx = it * 256 + tid;
    int t = idx >> 4;
    int d0 = (idx & 15) << 3;
    *reinterpret_cast<uint4*>(&qb[t][d0]) =
        *reinterpret_cast<const uint4*>(&phiQ[qbase + (size_t)t * DHEAD + d0]);
  }
  if (tid < 128) ks_l[tid] = ksp[(size_t)c * DHEAD + tid];
  if (h == 0) {
#pragma unroll
    for (int it = 0; it < 4; ++it) {
      int idx = it * 256 + tid;
      int t = idx >> 4;
      int d0 = (idx & 15) << 3;
      *reinterpret_cast<uint4*>(&kb[t][d0]) =
          *reinterpret_cast<const uint4*>(&phiK[kvbase + (size_t)t * DHEAD + d0]);
    }
    int t = tid & 63, dp = tid >> 6;
#pragma unroll
    for (int i = 0; i < 4; ++i) {
      int d0 = (dp + 4 * i) * 8;
      uint4 v4 = *reinterpret_cast<const uint4*>(&Vb[kvbase + (size_t)t * DHEAD + d0]);
      const unsigned short* vp = reinterpret_cast<const unsigned short*>(&v4);
#pragma unroll
      for (int j = 0; j < 8; ++j) vt[d0 + j][t] = vp[j];
    }
  } else {
#pragma unroll
    for (int it = 0; it < 8; ++it) {
      int idx = it * 256 + tid;
      int t = idx >> 4;
      int d0 = (idx & 15) << 3;
      *reinterpret_cast<uint4*>(&kb[t][d0]) =
          *reinterpret_cast<const uint4*>(&phiK[kvbase + (size_t)t * DHEAD + d0]);
    }
    int t = tid & 127, dp = tid >> 7;
#pragma unroll
    for (int i = 0; i < 8; ++i) {
      int d0 = (dp + 2 * i) * 8;
      uint4 v4 = *reinterpret_cast<const uint4*>(&Vb[kvbase + (size_t)t * DHEAD + d0]);
      const unsigned short* vp = reinterpret_cast<const unsigned short*>(&v4);
#pragma unroll
      for (int j = 0; j < 8; ++j) vt[d0 + j][t] = vp[j];
    }
  }
  __syncthreads();

  if (h == 0) {
    f32x4 sa[4];
#pragma unroll
    for (int i = 0; i < 4; ++i) sa[i] = (f32x4)0.0f;
#pragma unroll
    for (int ks = 0; ks < 4; ++ks) {
      int d0 = ks * 32 + kgrp * 8;
      bf16x8 af = *reinterpret_cast<const bf16x8*>(&qb[wave * 16 + lrow][d0]);
#pragma unroll
      for (int tc = 0; tc < 4; ++tc) {
        bf16x8 bf = *reinterpret_cast<const bf16x8*>(&kb[tc * 16 + lrow][d0]);
        sa[tc] = __builtin_amdgcn_mfma_f32_16x16x32_bf16(af, bf, sa[tc], 0, 0, 0);
      }
    }
    __syncthreads();
#pragma unroll
    for (int tc = 0; tc < 4; ++tc)
#pragma unroll
      for (int r = 0; r < 4; ++r) {
        int trow = wave * 16 + kgrp * 4 + r;
        int s = tc * 16 + lrow;
        kb[trow][s] = f2bf((s <= trow) ? sa[tc][r] : 0.0f);
      }
  } else {
    f32x4 sa[8];
#pragma unroll
    for (int i = 0; i < 8; ++i) sa[i] = (f32x4)0.0f;
#pragma unroll
    for (int ks = 0; ks < 4; ++ks) {
      int d0 = ks * 32 + kgrp * 8;
      bf16x8 af = *reinterpret_cast<const bf16x8*>(&qb[wave * 16 + lrow][d0]);
#pragma unroll
      for (int tc = 0; tc < 8; ++tc) {
        bf16x8 bf = *reinterpret_cast<const bf16x8*>(&kb[tc * 16 + lrow][d0]);
        sa[tc] = __builtin_amdgcn_mfma_f32_16x16x32_bf16(af, bf, sa[tc], 0, 0, 0);
      }
    }
    __syncthreads();
#pragma unroll
    for (int tc = 0; tc < 8; ++tc)
#pragma unroll
      for (int r = 0; r < 4; ++r) {
        int trow = wave * 16 + kgrp * 4 + r;
        int s = tc * 16 + lrow;
        kb[trow][s] = f2bf((s <= 64 + trow) ? sa[tc][r] : 0.0f);
      }
  }
  __syncthreads();   // P visible

  {
    int t = tid & 63, h4 = tid >> 6;
    float s = 0.0f;
    if (h4 < 2) {
      if (h4 == 0 || h == 1) {
        for (int j = h4 * 64; j < h4 * 64 + 64; ++j) s += bf2f(kb[t][j]);
      }
    } else {
      for (int j = (h4 - 2) * 64; j < (h4 - 2) * 64 + 64; ++j)
        s += bf2f(qb[t][j]) * ks_l[j];
    }
    dsum[h4][t] = s;
  }

  f32x4 acc[8];
#pragma unroll
  for (int i = 0; i < 8; ++i) acc[i] = (f32x4)0.0f;
  {
    const int nks = (h == 0) ? 2 : 4;
    for (int ks = 0; ks < nks; ++ks) {
      int t0 = ks * 32 + kgrp * 8;
      bf16x8 af = *reinterpret_cast<const bf16x8*>(&kb[wave * 16 + lrow][t0]);
#pragma unroll
      for (int tc = 0; tc < 8; ++tc) {
        bf16x8 bf = *reinterpret_cast<const bf16x8*>(&vt[tc * 16 + lrow][t0]);
        acc[tc] = __builtin_amdgcn_mfma_f32_16x16x32_bf16(af, bf, acc[tc], 0, 0, 0);
      }
    }
  }
  __syncthreads();

#pragma unroll
  for (int it = 0; it < 8; ++it) {
    int idx = it * 256 + tid;
    int dv = idx >> 4;
    int d0 = (idx & 15) << 3;
    *reinterpret_cast<uint4*>(&vt[dv][d0]) =
        *reinterpret_cast<const uint4*>(&KVp[(size_t)c * 16384 + (size_t)dv * DHEAD + d0]);
  }
  __syncthreads();

#pragma unroll
  for (int ks = 0; ks < 4; ++ks) {
    int d0 = ks * 32 + kgrp * 8;
    bf16x8 af = *reinterpret_cast<const bf16x8*>(&qb[wave * 16 + lrow][d0]);
#pragma unroll
    for (int tc = 0; tc < 8; ++tc) {
      bf16x8 bf = *reinterpret_cast<const bf16x8*>(&vt[tc * 16 + lrow][d0]);
      acc[tc] = __builtin_amdgcn_mfma_f32_16x16x32_bf16(af, bf, acc[tc], 0, 0, 0);
    }
  }

#pragma unroll
  for (int tc = 0; tc < 8; ++tc)
#pragma unroll
    for (int r = 0; r < 4; ++r) {
      int trow = wave * 16 + kgrp * 4 + r;
      int dv = tc * 16 + lrow;
      float den = dsum[0][trow] + dsum[1][trow] + dsum[2][trow] + dsum[3][trow];
      outp[qbase + (size_t)trow * DHEAD + dv] = acc[tc][r] / den;
    }
}

extern "C" void kernel_launch(void* const* d_in, const int* in_sizes, int n_in,
                              void* d_out, int out_size, void* d_ws, size_t ws_size,
                              hipStream_t stream) {
  const float* x  = (const float*)d_in[0];
  const float* Wq = (const float*)d_in[1];
  const float* Wk = (const float*)d_in[2];
  const float* Wv = (const float*)d_in[3];
  float* out = (float*)d_out;
  char* ws = (char*)d_ws;
  unsigned short* phiQ = (unsigned short*)(ws + 0);          // 4 MB
  unsigned short* phiK = (unsigned short*)(ws + 4194304);    // 4 MB
  unsigned short* Vb   = (unsigned short*)(ws + 8388608);    // 4 MB
  unsigned short* WT   = (unsigned short*)(ws + 12582912);   // 768 KB
  float*          KVc  = (float*)(ws + 13369344);            // 8 MB
  unsigned short* KVp  = (unsigned short*)(ws + 21757952);   // 4 MB
  float*          ksc  = (float*)(ws + 25952256);            // 64 KB
  float*          ksp  = (float*)(ws + 26017792);            // 64 KB

  transpose_w_kernel<<<1536, 256, 0, stream>>>(Wq, Wk, Wv, WT);
  proj_kernel<<<1024, 256, 0, stream>>>(x, WT, phiQ, phiK, Vb);
  chunkkv_kernel<<<dim3(128, 2), 256, 0, stream>>>(phiK, Vb, KVc, ksc);
  prefix_kernel<<<257, 256, 0, stream>>>(KVc, ksc, KVp, ksp);
  out_kernel<<<dim3(128, 2), 256, 0, stream>>>(phiQ, phiK, Vb, KVp, ksp, out);
}